// Round 8
// baseline (1427.797 us; speedup 1.0000x reference)
//
#include <hip/hip_runtime.h>
#include <hip/hip_bf16.h>
#include <math.h>

#define NN 100000
#define NE 1600000
#define DIM 128
#define NG 64
#define EPSBN 1e-5f
#define NGB 1563        // (NN+63)/64 conv tiles
#define SORT_WIN 12500  // NN/8 dst-window
#define NBINBLK 6250    // NE/256
#define DSL 64          // slices per window for deg2/scatter

typedef unsigned int u32;
typedef unsigned short u16;
typedef __attribute__((ext_vector_type(8))) short bf8_t;   // 8 x bf16
typedef __attribute__((ext_vector_type(4))) float f4_t;    // 4 x f32
typedef __attribute__((ext_vector_type(4))) unsigned short u16x4;
#define MFMA(a, b, c) __builtin_amdgcn_mfma_f32_16x16x32_bf16((a), (b), (c), 0, 0, 0)

__device__ __forceinline__ u16 f2bf(float f) {
    u32 u = __float_as_uint(f);
    u32 r = u + 0x7FFFu + ((u >> 16) & 1u);   // round-to-nearest-even
    return (u16)(r >> 16);
}
__device__ __forceinline__ float bf2f(u16 h) { return __uint_as_float(((u32)h) << 16); }

// ============ CSR build, XCD-partitioned ============
__global__ void k_bin_cnt(const int* __restrict__ ei, int* __restrict__ blkcnt) {
    __shared__ int c[8];
    int t = threadIdx.x;
    if (t < 8) c[t] = 0;
    __syncthreads();
    int e = blockIdx.x * 256 + t;
    int d = ei[NE + e];
    atomicAdd(&c[d / SORT_WIN], 1);
    __syncthreads();
    if (t < 8) blkcnt[blockIdx.x * 8 + t] = c[t];
}

__global__ void k_bin_scan(const int* __restrict__ blkcnt, int* __restrict__ blkoff,
                           int* __restrict__ wtotal) {
    __shared__ int ps[256];
    int w = blockIdx.x, t = threadIdx.x;
    const int PER = (NBINBLK + 255) / 256;  // 25
    int s = 0;
    for (int i = 0; i < PER; ++i) {
        int b = t * PER + i;
        if (b < NBINBLK) s += blkcnt[b * 8 + w];
    }
    ps[t] = s;
    for (int off = 1; off < 256; off <<= 1) {
        __syncthreads();
        int x = (t >= off) ? ps[t - off] : 0;
        __syncthreads();
        ps[t] += x;
    }
    __syncthreads();
    int run = (t ? ps[t - 1] : 0);
    for (int i = 0; i < PER; ++i) {
        int b = t * PER + i;
        if (b < NBINBLK) { blkoff[b * 8 + w] = run; run += blkcnt[b * 8 + w]; }
    }
    if (t == 255) wtotal[w] = ps[255];
}

__global__ void k_bin_start(const int* __restrict__ wtotal, int* __restrict__ binStart) {
    if (threadIdx.x == 0) {
        int a = 0;
        for (int w = 0; w < 8; ++w) { binStart[w] = a; a += wtotal[w]; }
        binStart[8] = a;
    }
}

__global__ void k_bin_place(const int* __restrict__ ei, const int* __restrict__ blkoff,
                            const int* __restrict__ binStart, int2* __restrict__ binned) {
    __shared__ int base[8];
    int t = threadIdx.x;
    if (t < 8) base[t] = binStart[t] + blkoff[blockIdx.x * 8 + t];
    __syncthreads();
    int e = blockIdx.x * 256 + t;
    int s = ei[e], d = ei[NE + e];
    int pos = atomicAdd(&base[d / SORT_WIN], 1);
    binned[pos] = make_int2(s, d);
}

__global__ void k_deg2(const int2* __restrict__ binned, const int* __restrict__ binStart,
                       int* __restrict__ deg) {
    int w = blockIdx.x & 7, sl = blockIdx.x >> 3;
    int b0 = binStart[w], b1 = binStart[w + 1];
    int chunk = (b1 - b0 + DSL - 1) / DSL;
    int r0 = b0 + sl * chunk, r1 = min(r0 + chunk, b1);
    for (int i = r0 + threadIdx.x; i < r1; i += 256)
        atomicAdd(&deg[binned[i].y], 1);
}

__global__ void k_scatter(const int2* __restrict__ binned, const int* __restrict__ binStart,
                          int* __restrict__ cursor, int* __restrict__ sorted_src) {
    int w = blockIdx.x & 7, sl = blockIdx.x >> 3;
    int b0 = binStart[w], b1 = binStart[w + 1];
    int chunk = (b1 - b0 + DSL - 1) / DSL;
    int r0 = b0 + sl * chunk, r1 = min(r0 + chunk, b1);
    for (int i = r0 + threadIdx.x; i < r1; i += 256) {
        int2 e = binned[i];
        int pos = atomicAdd(&cursor[e.y], 1);
        sorted_src[pos] = e.x;
    }
}

#define SCAN_B 256
__global__ void k_scan1(const int* __restrict__ deg, int* __restrict__ row_start,
                        int* __restrict__ bsum, float* __restrict__ inv_deg) {
    __shared__ int s[SCAN_B];
    int t = threadIdx.x;
    int i = blockIdx.x * SCAN_B + t;
    int v = (i < NN) ? deg[i] : 0;
    if (i < NN) inv_deg[i] = 1.0f / (float)(v > 1 ? v : 1);
    s[t] = v;
    for (int off = 1; off < SCAN_B; off <<= 1) {
        __syncthreads();
        int x = (t >= off) ? s[t - off] : 0;
        __syncthreads();
        s[t] += x;
    }
    if (i < NN) row_start[i + 1] = s[t];
    if (t == SCAN_B - 1) bsum[blockIdx.x] = s[t];
}

__global__ void k_scan2(int* __restrict__ bsum, int nb) {
    __shared__ int s[512];
    int t = threadIdx.x;
    int v = (t < nb) ? bsum[t] : 0;
    s[t] = v;
    for (int off = 1; off < 512; off <<= 1) {
        __syncthreads();
        int x = (t >= off) ? s[t - off] : 0;
        __syncthreads();
        s[t] += x;
    }
    if (t < nb) bsum[t] = s[t] - v;
}

__global__ void k_scan3(int* __restrict__ row_start, const int* __restrict__ bsum,
                        int* __restrict__ cursor) {
    int i = blockIdx.x * blockDim.x + threadIdx.x;
    if (i < NN) {
        int v = row_start[i + 1] + bsum[i / SCAN_B];
        row_start[i + 1] = v;
        if (i + 1 < NN) cursor[i + 1] = v;
    }
    if (i == 0) { row_start[0] = 0; cursor[0] = 0; }
}

__global__ void k_bounds(const int* __restrict__ batch, int* __restrict__ gs) {
    int g = threadIdx.x;
    if (g > NG) return;
    int lo = 0, hi = NN;
    while (lo < hi) {
        int mid = (lo + hi) >> 1;
        if (batch[mid] < g) lo = mid + 1; else hi = mid;
    }
    gs[g] = lo;
}

// ---------------- fp32 x -> split bf16 (hi, lo) ----------------
__global__ void k_split_x(const float* __restrict__ x, u16* __restrict__ Xh,
                          u16* __restrict__ Xl) {
    int idx = blockIdx.x * 256 + threadIdx.x;
    int base = idx * 4;
    float4 v = *reinterpret_cast<const float4*>(&x[base]);
    u16x4 hi, lo;
    float vv[4] = {v.x, v.y, v.z, v.w};
#pragma unroll
    for (int j = 0; j < 4; j++) {
        u16 h = f2bf(vv[j]);
        hi[j] = h;
        lo[j] = f2bf(vv[j] - bf2f(h));
    }
    *reinterpret_cast<u16x4*>(&Xh[base]) = hi;
    *reinterpret_cast<u16x4*>(&Xl[base]) = lo;
}

// ---------------- weight prep: transpose+stack+split ----------------
__global__ void k_prep_w(const float* __restrict__ Wl, const float* __restrict__ Wr,
                         u16* __restrict__ Wth, u16* __restrict__ Wtl) {
    int idx = blockIdx.x * 256 + threadIdx.x;  // 8*128*256
    int k = idx & 255;
    int col = (idx >> 8) & 127;
    int c = idx >> 15;
    float v = (k < 128) ? Wl[(c * 128 + k) * 128 + col] : Wr[(c * 128 + (k - 128)) * 128 + col];
    u16 h = f2bf(v);
    Wth[idx] = h;
    Wtl[idx] = f2bf(v - bf2f(h));
}

// in-register: v = relu(affine(hi+lo)); re-split
__device__ __forceinline__ void affine_split(bf8_t& h, bf8_t& l,
                                             const float* __restrict__ ss, int k0) {
#pragma unroll
    for (int j = 0; j < 8; ++j) {
        float v = bf2f((u16)h[j]) + bf2f((u16)l[j]);
        v = fmaxf(v * ss[k0 + j] + ss[128 + k0 + j], 0.f);
        u16 hh = f2bf(v);
        h[j] = (short)hh;
        l[j] = (short)f2bf(v - bf2f(hh));
    }
}

// ================= FUSED conv: gather-mean + dual GEMM =================
// 512 thr = 8 waves; tile = 64 rows x 128 cols; grid NGB.
// Phase 0: DMA own rows (Ah/Al) -> sX via global_load_lds (src pre-swizzled).
// Phase 1: each wave gathers 8 nodes' neighbor means (hi-only) -> sAgg (swizzled).
// Phase 2: GEMM; wave w owns cols [w*16,w*16+16); agg half 2 MFMA, X half 3 MFMA.
// LDS 49KB -> 3 blocks/CU (24 waves) keeps gather TLP high.
template <bool AFFG, bool STATS, bool AFF2, bool RELU>
__global__ __launch_bounds__(512, 6) void k_conv(
    const u16* __restrict__ Ah, const u16* __restrict__ Al,
    const int* __restrict__ row_start, const int* __restrict__ ssrc,
    const float* __restrict__ inv_deg,
    const u16* __restrict__ Wth, const u16* __restrict__ Wtl,
    const float* __restrict__ bias, const float* __restrict__ ss,
    u16* __restrict__ Oh, u16* __restrict__ Ol,
    float* __restrict__ partials) {
    __shared__ u16 sAgg[64][128];     // 16KB, agg hi, chunk-XOR swizzled
    __shared__ u16 sX[2][64][128];    // 32KB, own rows hi/lo, swizzled
    __shared__ float cs[128], cq[128];
    int t = threadIdx.x;
    int w = t >> 6, l = t & 63;
    int rbase = blockIdx.x * 64;

    // ---- phase 0: stage own rows (hi,lo) via DMA, source-side inverse swizzle ----
#pragma unroll
    for (int R = 0; R < 2; ++R) {
        const u16* src = R ? Al : Ah;
#pragma unroll
        for (int i = 0; i < 2; ++i) {
            int slot = i * 512 + t;              // 16B slots: 64 rows x 16 chunks
            int row = slot >> 4, cm = slot & 15;
            int cd = cm ^ (row & 7);
            int rowc = min(rbase + row, NN - 1);
            const u16* g = src + (size_t)rowc * DIM + cd * 8;
            u16* lp = &sX[R][0][0] + (size_t)(i * 512 + w * 64) * 8;  // wave-uniform base
            __builtin_amdgcn_global_load_lds(
                (const __attribute__((address_space(1))) void*)g,
                (__attribute__((address_space(3))) void*)lp, 16, 0, 0);
        }
    }

    // ---- phase 1: gather 8 nodes per wave (hi-only), write sAgg ----
    {
        int half = l >> 5;
        int cl = l & 31;   // cols [cl*4, cl*4+4)
        float sc0 = 0.f, sc1 = 0.f, sc2 = 0.f, sc3 = 0.f;
        float sh0 = 0.f, sh1 = 0.f, sh2 = 0.f, sh3 = 0.f;
        if (AFFG) {
            float4 s4 = *reinterpret_cast<const float4*>(ss + cl * 4);
            float4 h4 = *reinterpret_cast<const float4*>(ss + 128 + cl * 4);
            sc0 = s4.x; sc1 = s4.y; sc2 = s4.z; sc3 = s4.w;
            sh0 = h4.x; sh1 = h4.y; sh2 = h4.z; sh3 = h4.w;
        }
        for (int q = 0; q < 8; ++q) {
            int wid = rbase + w * 8 + q;
            if (wid < NN) {
                int beg = row_start[wid], end = row_start[wid + 1];
                int n = end - beg;
                float a0 = 0.f, a1 = 0.f, a2 = 0.f, a3 = 0.f;
#define ACCUM(vv)                                                                   \
    {                                                                               \
        float t0 = __uint_as_float((vv).x << 16);                                   \
        float t1 = __uint_as_float((vv).x & 0xFFFF0000u);                           \
        float t2 = __uint_as_float((vv).y << 16);                                   \
        float t3 = __uint_as_float((vv).y & 0xFFFF0000u);                           \
        if (AFFG) {                                                                 \
            t0 = fmaxf(t0 * sc0 + sh0, 0.f); t1 = fmaxf(t1 * sc1 + sh1, 0.f);       \
            t2 = fmaxf(t2 * sc2 + sh2, 0.f); t3 = fmaxf(t3 * sc3 + sh3, 0.f);       \
        }                                                                           \
        a0 += t0; a1 += t1; a2 += t2; a3 += t3;                                     \
    }
                for (int base = 0; base < n; base += 64) {
                    int rem = n - base;
                    int idx = beg + base + (l < rem ? l : 0);
                    int sv = ssrc[idx];
                    int m = rem < 64 ? rem : 64;
                    int j = 0;
                    for (; j + 4 <= m; j += 4) {
                        int sA = __shfl(sv, j + half);
                        int sB = __shfl(sv, j + 2 + half);
                        uint2 vA = *reinterpret_cast<const uint2*>(
                            reinterpret_cast<const u32*>(Ah + (size_t)sA * DIM) + cl * 2);
                        uint2 vB = *reinterpret_cast<const uint2*>(
                            reinterpret_cast<const u32*>(Ah + (size_t)sB * DIM) + cl * 2);
                        ACCUM(vA); ACCUM(vB);
                    }
                    for (; j < m; j += 2) {
                        if (j + half < m) {
                            int s0 = __shfl(sv, j + half);
                            uint2 v = *reinterpret_cast<const uint2*>(
                                reinterpret_cast<const u32*>(Ah + (size_t)s0 * DIM) + cl * 2);
                            ACCUM(v);
                        }
                    }
                }
#undef ACCUM
                a0 += __shfl_down(a0, 32);
                a1 += __shfl_down(a1, 32);
                a2 += __shfl_down(a2, 32);
                a3 += __shfl_down(a3, 32);
                if (half == 0) {
                    float sc = inv_deg[wid];
                    a0 *= sc; a1 *= sc; a2 *= sc; a3 *= sc;
                    u32 p0 = (u32)f2bf(a0) | ((u32)f2bf(a1) << 16);
                    u32 p1 = (u32)f2bf(a2) | ((u32)f2bf(a3) << 16);
                    int row = w * 8 + q;
                    // swizzled: chunk (cl>>1) -> (cl>>1)^(row&7), 8B sub-offset (cl&1)
                    u16* dst = &sAgg[row][(((cl >> 1) ^ (row & 7)) << 3) + ((cl & 1) << 2)];
                    *reinterpret_cast<uint2*>(dst) = make_uint2(p0, p1);
                }
            }
        }
    }
    asm volatile("s_waitcnt vmcnt(0)" ::: "memory");
    __syncthreads();

    // ---- phase 2: GEMM, wave w -> cols [w*16, w*16+16) ----
    int rl = l & 15, kg = l >> 4;
    int col0 = w * 16;
    f4_t acc[4];
#pragma unroll
    for (int i = 0; i < 4; ++i) acc[i] = (f4_t){0.f, 0.f, 0.f, 0.f};

#pragma unroll
    for (int kc = 0; kc < 8; ++kc) {
        bf8_t wh = *reinterpret_cast<const bf8_t*>(
            Wth + (size_t)(col0 + rl) * 256 + kc * 32 + kg * 8);
        bf8_t wl_ = *reinterpret_cast<const bf8_t*>(
            Wtl + (size_t)(col0 + rl) * 256 + kc * 32 + kg * 8);
#pragma unroll
        for (int rf = 0; rf < 4; ++rf) {
            int row = rf * 16 + rl;
            int cd = (((kc & 3) * 4 + kg) ^ (row & 7)) * 8;
            if (kc < 4) {
                bf8_t aH = *reinterpret_cast<const bf8_t*>(&sAgg[row][cd]);
                acc[rf] = MFMA(aH, wh, acc[rf]);
                acc[rf] = MFMA(aH, wl_, acc[rf]);
            } else {
                bf8_t aH = *reinterpret_cast<const bf8_t*>(&sX[0][row][cd]);
                bf8_t aL = *reinterpret_cast<const bf8_t*>(&sX[1][row][cd]);
                if (AFF2) {
                    int k0 = (kc - 4) * 32 + kg * 8;
                    affine_split(aH, aL, ss, k0);
                }
                acc[rf] = MFMA(aH, wh, acc[rf]);
                acc[rf] = MFMA(aH, wl_, acc[rf]);
                acc[rf] = MFMA(aL, wh, acc[rf]);
            }
        }
    }

    // ---- epilogue: D layout col=lane&15, row=(lane>>4)*4+i [verified m89] ----
    float bv = bias[col0 + rl];
    float s0 = 0.f, q0 = 0.f;
#pragma unroll
    for (int rf = 0; rf < 4; ++rf) {
#pragma unroll
        for (int i = 0; i < 4; ++i) {
            int row = rbase + rf * 16 + kg * 4 + i;
            if (row < NN) {
                float v = acc[rf][i] + bv;
                if (RELU) v = fmaxf(v, 0.f);
                u16 hi = f2bf(v);
                Oh[(size_t)row * DIM + col0 + rl] = hi;
                Ol[(size_t)row * DIM + col0 + rl] = f2bf(v - bf2f(hi));
                if (STATS) { s0 += v; q0 += v * v; }
            }
        }
    }
    if (STATS) {
        s0 += __shfl_xor(s0, 16); s0 += __shfl_xor(s0, 32);
        q0 += __shfl_xor(q0, 16); q0 += __shfl_xor(q0, 32);
        if (l < 16) {  // wave-exclusive cols -> plain stores
            cs[col0 + rl] = s0;
            cq[col0 + rl] = q0;
        }
        __syncthreads();
        if (t < 256) partials[(size_t)blockIdx.x * 256 + t] = (t < 128) ? cs[t] : cq[t - 128];
    }
}

// ---------------- BN: two-stage parallel reduce -> scale/shift ----------------
__global__ void k_bn_r1(const float* __restrict__ partials, float* __restrict__ colpart) {
    int t = threadIdx.x;
    int b = blockIdx.x;  // 32 blocks
    int b0 = b * 49, b1 = min(b0 + 49, NGB);
    float s = 0.f;
    for (int i = b0; i < b1; ++i) s += partials[i * 256 + t];
    colpart[b * 256 + t] = s;
}

__global__ void k_bn_r2(const float* __restrict__ colpart, const float* __restrict__ gamma,
                        const float* __restrict__ beta, float* __restrict__ scaleshift) {
    __shared__ float sm[256];
    int t = threadIdx.x;
    float s = 0.f;
#pragma unroll
    for (int b = 0; b < 32; ++b) s += colpart[b * 256 + t];
    sm[t] = s;
    __syncthreads();
    if (t < 128) {
        float mu = sm[t] * (1.0f / NN);
        float var = sm[t + 128] * (1.0f / NN) - mu * mu;
        float sc = rsqrtf(var + EPSBN) * gamma[t];
        scaleshift[t] = sc;
        scaleshift[t + 128] = beta[t] - mu * sc;
    }
}

// ---------------- pooling: hi-only + fused BN+relu ----------------
__global__ void k_pool(const u16* __restrict__ Hh, const int* __restrict__ gs,
                       const float* __restrict__ ss,
                       float* __restrict__ pSum, float* __restrict__ pMax) {
    int g = blockIdx.x >> 3, slice = blockIdx.x & 7;
    int s0 = gs[g], s1 = gs[g + 1];
    int len = s1 - s0;
    int chunk = (len + 7) >> 3;
    int r0 = s0 + slice * chunk;
    int r1 = min(r0 + chunk, s1);
    int t = threadIdx.x;
    int c2 = (t & 63) * 2, half = t >> 6;
    float sc0 = ss[c2], sc1 = ss[c2 + 1];
    float sh0 = ss[128 + c2], sh1 = ss[128 + c2 + 1];
    float sa = 0.f, sb = 0.f, ma = 0.f, mb = 0.f;
    for (int r = r0 + half; r < r1; r += 4) {
        u32 h2 = *reinterpret_cast<const u32*>(Hh + r * DIM + c2);
        float v0 = fmaxf(__uint_as_float(h2 << 16) * sc0 + sh0, 0.f);
        float v1 = fmaxf(__uint_as_float(h2 & 0xFFFF0000u) * sc1 + sh1, 0.f);
        sa += v0; sb += v1;
        ma = fmaxf(ma, v0); mb = fmaxf(mb, v1);
    }
    __shared__ float ls[4][128], lm[4][128];
    ls[half][c2] = sa; ls[half][c2 + 1] = sb;
    lm[half][c2] = ma; lm[half][c2 + 1] = mb;
    __syncthreads();
    if (t < 128) {
        float s = ls[0][t] + ls[1][t] + ls[2][t] + ls[3][t];
        float m = fmaxf(fmaxf(lm[0][t], lm[1][t]), fmaxf(lm[2][t], lm[3][t]));
        atomicAdd(&pSum[g * DIM + t], s);
        atomicMax((int*)&pMax[g * DIM + t], __float_as_int(m));  // values >= 0, init 0
    }
}

// ---------------- classifier MLP: one block per graph ----------------
__global__ void k_mlp(const float* __restrict__ pSum, const float* __restrict__ pMax,
                      const int* __restrict__ gs,
                      const float* __restrict__ W1, const float* __restrict__ b1,
                      const float* __restrict__ W2, const float* __restrict__ b2,
                      const float* __restrict__ W3, const float* __restrict__ b3,
                      float* __restrict__ out) {
    __shared__ float g[256], y1[128], y2[64];
    int gi = blockIdx.x;
    int t = threadIdx.x;  // 128 threads
    int cnt = gs[gi + 1] - gs[gi];
    float inv = 1.0f / fmaxf((float)cnt, 1.0f);
    g[t] = pSum[gi * DIM + t] * inv;
    g[128 + t] = pMax[gi * DIM + t];
    __syncthreads();
    float a = b1[t];
    for (int k = 0; k < 256; k++) a += g[k] * W1[k * 128 + t];
    y1[t] = fmaxf(a, 0.f);
    __syncthreads();
    if (t < 64) {
        float a2 = b2[t];
        for (int k = 0; k < 128; k++) a2 += y1[k] * W2[k * 64 + t];
        y2[t] = fmaxf(a2, 0.f);
    }
    __syncthreads();
    if (t < 64) {
        float p = y2[t] * W3[t];
#pragma unroll
        for (int off = 32; off; off >>= 1) p += __shfl_down(p, off);
        if (t == 0) out[gi] = p + b3[0];
    }
}

extern "C" void kernel_launch(void* const* d_in, const int* in_sizes, int n_in,
                              void* d_out, int out_size, void* d_ws, size_t ws_size,
                              hipStream_t stream) {
    const float* x     = (const float*)d_in[0];
    const int*   ei    = (const int*)d_in[1];
    const int*   batch = (const int*)d_in[2];
    const float* Wl    = (const float*)d_in[3];
    const float* bl    = (const float*)d_in[4];
    const float* Wr    = (const float*)d_in[5];
    const float* gamma = (const float*)d_in[6];
    const float* beta  = (const float*)d_in[7];
    const float* W1    = (const float*)d_in[8];
    const float* b1    = (const float*)d_in[9];
    const float* W2    = (const float*)d_in[10];
    const float* b2    = (const float*)d_in[11];
    const float* W3    = (const float*)d_in[12];
    const float* b3    = (const float*)d_in[13];
    float* out = (float*)d_out;

    char* p = (char*)d_ws;
    size_t off = 0;
    auto alloc = [&](size_t bytes) -> void* {
        void* r = p + off;
        off += (bytes + 255) & ~(size_t)255;
        return r;
    };
    const size_t HB = (size_t)NN * DIM * 2;
    u16* Xh   = (u16*)alloc(HB);   // block input / conv2 output (pre-BN), ping-pong
    u16* Xl   = (u16*)alloc(HB);
    u16* hAh  = (u16*)alloc(HB);
    u16* hAl  = (u16*)alloc(HB);
    int2*  binned    = (int2*)alloc((size_t)NE * 8);
    int*   ssrc      = (int*)alloc((size_t)NE * 4);
    u16*   Wth       = (u16*)alloc((size_t)8 * 128 * 256 * 2);
    u16*   Wtl       = (u16*)alloc((size_t)8 * 128 * 256 * 2);
    float* partials  = (float*)alloc((size_t)NGB * 256 * 4);
    float* colpart   = (float*)alloc(32 * 256 * 4);
    int*   deg       = (int*)alloc(NN * 4);
    float* inv_deg   = (float*)alloc(NN * 4);
    int*   row_start = (int*)alloc((NN + 1) * 4);
    int*   cursor    = (int*)alloc(NN * 4);
    int*   bsum      = (int*)alloc(512 * 4);
    int*   gs        = (int*)alloc((NG + 1) * 4);
    int*   blkcnt    = (int*)alloc((size_t)NBINBLK * 8 * 4);
    int*   blkoff    = (int*)alloc((size_t)NBINBLK * 8 * 4);
    int*   wtotal    = (int*)alloc(8 * 4);
    int*   binStart  = (int*)alloc(9 * 4);
    float* ssb       = (float*)alloc(4 * 256 * 4);   // per-block scale/shift
    float* pSum      = (float*)alloc(NG * DIM * 4);
    float* pMax      = (float*)alloc(NG * DIM * 4);

    const int nbN = (NN + 255) / 256;
    const int nbQ = NN * DIM / 4 / 256;  // 12500

    // ---- CSR build (XCD-partitioned) ----
    hipMemsetAsync(deg, 0, NN * 4, stream);
    k_bin_cnt<<<NBINBLK, 256, 0, stream>>>(ei, blkcnt);
    k_bin_scan<<<8, 256, 0, stream>>>(blkcnt, blkoff, wtotal);
    k_bin_start<<<1, 64, 0, stream>>>(wtotal, binStart);
    k_bin_place<<<NBINBLK, 256, 0, stream>>>(ei, blkoff, binStart, binned);
    k_deg2<<<8 * DSL, 256, 0, stream>>>(binned, binStart, deg);
    k_scan1<<<nbN, 256, 0, stream>>>(deg, row_start, bsum, inv_deg);
    k_scan2<<<1, 512, 0, stream>>>(bsum, nbN);
    k_scan3<<<nbN, 256, 0, stream>>>(row_start, bsum, cursor);
    k_scatter<<<8 * DSL, 256, 0, stream>>>(binned, binStart, cursor, ssrc);
    k_bounds<<<1, 128, 0, stream>>>(batch, gs);

    // ---- input + weight prep ----
    k_split_x<<<nbQ, 256, 0, stream>>>(x, Xh, Xl);
    k_prep_w<<<8 * 128 * 256 / 256, 256, 0, stream>>>(Wl, Wr, Wth, Wtl);

    for (int b = 0; b < 4; b++) {
        int c0 = 2 * b, c1 = 2 * b + 1;
        const u16* W0h = Wth + (size_t)c0 * 128 * 256;
        const u16* W0l = Wtl + (size_t)c0 * 128 * 256;
        const u16* W1h = Wth + (size_t)c1 * 128 * 256;
        const u16* W1l = Wtl + (size_t)c1 * 128 * 256;
        const float* ssPrev = ssb + (size_t)(b > 0 ? b - 1 : 0) * 256;
        // conv1: gather+GEMM fused; input transform relu∘affine for b>0
        if (b == 0) {
            k_conv<false, false, false, true><<<NGB, 512, 0, stream>>>(
                Xh, Xl, row_start, ssrc, inv_deg, W0h, W0l, bl + c0 * DIM, ssPrev,
                hAh, hAl, partials);
        } else {
            k_conv<true, false, true, true><<<NGB, 512, 0, stream>>>(
                Xh, Xl, row_start, ssrc, inv_deg, W0h, W0l, bl + c0 * DIM, ssPrev,
                hAh, hAl, partials);
        }
        // conv2 (+stats), output pre-BN into Xh/Xl
        k_conv<false, true, false, false><<<NGB, 512, 0, stream>>>(
            hAh, hAl, row_start, ssrc, inv_deg, W1h, W1l, bl + c1 * DIM, ssPrev,
            Xh, Xl, partials);
        k_bn_r1<<<32, 256, 0, stream>>>(partials, colpart);
        k_bn_r2<<<1, 256, 0, stream>>>(colpart, gamma + b * DIM, beta + b * DIM,
                                       ssb + (size_t)b * 256);
    }

    // ---- pooling (fused BN+relu) + classifier ----
    hipMemsetAsync(pSum, 0, NG * DIM * 4, stream);
    hipMemsetAsync(pMax, 0, NG * DIM * 4, stream);
    k_pool<<<NG * 8, 256, 0, stream>>>(Xh, gs, ssb + 3 * 256, pSum, pMax);
    k_mlp<<<NG, 128, 0, stream>>>(pSum, pMax, gs, W1, b1, W2, b2, W3, b3, out);
}